// Round 1
// baseline (768.837 us; speedup 1.0000x reference)
//
#include <hip/hip_runtime.h>

// GroupMLP: y = (BN(x@w1+b1) relu) @ w2 + b2, per-head (H=8), training-mode BN over N.
// Strategy: bf16 MFMA (16x16x32). Pass1 computes per-(h,c) sum/sumsq of h_pre
// (recompute trick: no h materialization). Pass2 recomputes GEMM1 and fuses
// BN(as per-channel affine)+ReLU+GEMM2.
//
// ws layout: w1bf[8*128*128] bf16 (transposed [h][o][i]) | w2bf[8*64*128] bf16
// ([h][o][i]) | partial[8][nblk][256] f32 (128 sum + 128 sumsq per block) |
// acoef[1024] | bcoef[1024].  ~3.5 MB total.

#define H_HEADS 8
#define F_IN 128
#define HID 128
#define F_OUT 64
#define EPS 1e-5f
#define LDP 136   // LDS row pitch in bf16 elems (128 + 8 pad -> 272B, 16B-aligned)

typedef __bf16 bf16x8 __attribute__((ext_vector_type(8)));
typedef float f32x4 __attribute__((ext_vector_type(4)));

__device__ __forceinline__ unsigned short f2bf(float f) {
  union { float f; unsigned u; } v; v.f = f;
  unsigned r = v.u + 0x7FFFu + ((v.u >> 16) & 1u);
  return (unsigned short)(r >> 16);
}

// ---- K0: convert weights to bf16, transposed to [h][o][i] for B-fragment reads
__global__ void k_prep(const float* __restrict__ w1, const float* __restrict__ w2,
                       unsigned short* __restrict__ w1bf, unsigned short* __restrict__ w2bf) {
  int idx = blockIdx.x * 256 + threadIdx.x;       // 0 .. 131071
  {
    int h = idx >> 14, rest = idx & 16383;
    int o = rest >> 7, i = rest & 127;
    w1bf[idx] = f2bf(w1[(h << 14) + (i << 7) + o]);   // w1[h][i][o]
  }
  if (idx < 65536) {
    int h = idx >> 13, rest = idx & 8191;
    int o = rest >> 7, i = rest & 127;
    w2bf[idx] = f2bf(w2[(h << 13) + (i << 6) + o]);   // w2[h][i][o], o<64
  }
}

// ---- K1: stats pass. Each block: head hh, 4 chunks of 64 rows. GEMM1 via MFMA,
// accumulate per-channel sum/sumsq of (x@w1 + b1), write per-block partials.
__launch_bounds__(256, 2)
__global__ void k_stats(const float* __restrict__ x, const unsigned short* __restrict__ w1bf,
                        const float* __restrict__ b1, float* __restrict__ partial,
                        int N, int nblk) {
  __shared__ unsigned short w1s[128 * LDP];
  __shared__ unsigned short xb[64 * LDP];
  __shared__ float psum[512], psq[512];
  __shared__ float b1s[128];

  const int tid = threadIdx.x;
  const int hh = blockIdx.y;
  const int bi = blockIdx.x;
  const int lane = tid & 63, wv = tid >> 6;
  const int m = lane & 15, q = lane >> 4;

  // stage w1T (bf16) for this head: 128 rows x 128
  {
    const uint4* src = (const uint4*)(w1bf + (hh << 14) + ((tid >> 1) << 7) + (tid & 1) * 64);
    uint4* dst = (uint4*)(w1s + (tid >> 1) * LDP + (tid & 1) * 64);
#pragma unroll
    for (int j = 0; j < 8; j++) dst[j] = src[j];
  }
  if (tid < 128) b1s[tid] = b1[hh * 128 + tid];

  float s[8] = {0, 0, 0, 0, 0, 0, 0, 0};
  float ss[8] = {0, 0, 0, 0, 0, 0, 0, 0};

  for (int it = 0; it < 4; it++) {
    const int r0 = (bi * 4 + it) * 64;
    if (r0 >= N) break;
    // stage x tile 64x128 -> bf16 LDS (zero-pad tail rows)
    {
      int r = tid >> 2, cs = (tid & 3) * 32;
      unsigned short* dst = xb + r * LDP + cs;
      if (r0 + r < N) {
        const float4* xp = (const float4*)(x + (((size_t)(r0 + r) * 8 + hh) << 7) + cs);
#pragma unroll
        for (int j = 0; j < 8; j++) {
          float4 f = xp[j];
          ushort4 sv = {f2bf(f.x), f2bf(f.y), f2bf(f.z), f2bf(f.w)};
          ((ushort4*)dst)[j] = sv;
        }
      } else {
        ushort4 zz = {0, 0, 0, 0};
#pragma unroll
        for (int j = 0; j < 8; j++) ((ushort4*)dst)[j] = zz;
      }
    }
    __syncthreads();

    // GEMM1: wave wv computes rows [wv*16, wv*16+16) x all 128 cols
    f32x4 acc[8] = {};
    const unsigned short* arow = xb + (wv * 16 + m) * LDP + q * 8;
    const unsigned short* bbase = w1s + m * LDP + q * 8;
#pragma unroll
    for (int kk = 0; kk < 4; kk++) {
      bf16x8 af = *(const bf16x8*)(arow + kk * 32);
#pragma unroll
      for (int nt = 0; nt < 8; nt++) {
        bf16x8 bfr = *(const bf16x8*)(bbase + nt * 16 * LDP + kk * 32);
        acc[nt] = __builtin_amdgcn_mfma_f32_16x16x32_bf16(af, bfr, acc[nt], 0, 0, 0);
      }
    }

    // accumulate sum/sumsq of h_pre = acc + b1 over valid rows
    const int rowb = r0 + wv * 16 + q * 4;
#pragma unroll
    for (int nt = 0; nt < 8; nt++) {
      float bc = b1s[nt * 16 + m];
#pragma unroll
      for (int r = 0; r < 4; r++) {
        float v = ((rowb + r) < N) ? (acc[nt][r] + bc) : 0.f;
        s[nt] += v;
        ss[nt] += v * v;
      }
    }
    __syncthreads();  // xb WAR before next chunk
  }

  // reduce across quads (rows within wave), then waves, then write partials
#pragma unroll
  for (int nt = 0; nt < 8; nt++) {
    float a = s[nt], b = ss[nt];
    a += __shfl_xor(a, 16); b += __shfl_xor(b, 16);
    a += __shfl_xor(a, 32); b += __shfl_xor(b, 32);
    if (q == 0) {
      psum[wv * 128 + nt * 16 + m] = a;
      psq[wv * 128 + nt * 16 + m] = b;
    }
  }
  __syncthreads();
  if (tid < 128) {
    float a = psum[tid] + psum[tid + 128] + psum[tid + 256] + psum[tid + 384];
    float b = psq[tid] + psq[tid + 128] + psq[tid + 256] + psq[tid + 384];
    float* base = partial + ((size_t)hh * nblk + bi) * 256;
    base[tid] = a;
    base[tid + 128] = b;
  }
}

// ---- K2: reduce partials -> mean/var -> fold BN+b1 into per-channel affine
__global__ void k_fin(const float* __restrict__ partial, const float* __restrict__ b1,
                      const float* __restrict__ bnw, const float* __restrict__ bnb,
                      float* __restrict__ acoef, float* __restrict__ bcoef,
                      int N, int nblk) {
  int hc = blockIdx.x * 256 + threadIdx.x;  // 0..2047
  int h = hc >> 7, c = hc & 127;
  const float* p = partial + ((size_t)h * nblk) * 256 + c;
  float s = 0.f, ss = 0.f;
#pragma unroll 8
  for (int i = 0; i < nblk; i++) {
    s += p[(size_t)i * 256];
    ss += p[(size_t)i * 256 + 128];
  }
  float mean = s / (float)N;
  float var = ss / (float)N - mean * mean;
  float a = bnw[hc] * rsqrtf(var + EPS);
  acoef[hc] = a;
  bcoef[hc] = (b1[hc] - mean) * a + bnb[hc];  // h_bn = (x@w1)*a + bcoef
}

// ---- K3: main pass. GEMM1 -> affine+ReLU -> (LDS round-trip to A-layout) -> GEMM2 -> y
__launch_bounds__(256, 2)
__global__ void k_main(const float* __restrict__ x, const unsigned short* __restrict__ w1bf,
                       const unsigned short* __restrict__ w2bf,
                       const float* __restrict__ acoef, const float* __restrict__ bcoef,
                       const float* __restrict__ b2, float* __restrict__ y,
                       int N, int nblk) {
  __shared__ unsigned short w1s[128 * LDP];
  __shared__ unsigned short w2s[64 * LDP];
  __shared__ unsigned short xb[64 * LDP];  // reused as hb (relu'd bf16) for GEMM2
  __shared__ float acs[128], bcs[128], b2s[64];

  const int tid = threadIdx.x;
  const int hh = blockIdx.y;
  const int bi = blockIdx.x;
  const int lane = tid & 63, wv = tid >> 6;
  const int m = lane & 15, q = lane >> 4;

  {
    const uint4* src = (const uint4*)(w1bf + (hh << 14) + ((tid >> 1) << 7) + (tid & 1) * 64);
    uint4* dst = (uint4*)(w1s + (tid >> 1) * LDP + (tid & 1) * 64);
#pragma unroll
    for (int j = 0; j < 8; j++) dst[j] = src[j];
  }
  {
    const uint4* src = (const uint4*)(w2bf + (hh << 13) + ((tid >> 2) << 7) + (tid & 3) * 32);
    uint4* dst = (uint4*)(w2s + (tid >> 2) * LDP + (tid & 3) * 32);
#pragma unroll
    for (int j = 0; j < 4; j++) dst[j] = src[j];
  }
  if (tid < 128) {
    acs[tid] = acoef[hh * 128 + tid];
    bcs[tid] = bcoef[hh * 128 + tid];
  }
  if (tid < 64) b2s[tid] = b2[hh * 64 + tid];

  for (int it = 0; it < 4; it++) {
    const int r0 = (bi * 4 + it) * 64;
    if (r0 >= N) break;
    __syncthreads();  // covers weight/coef staging (it=0) and hb WAR (it>0)

    // stage x tile
    {
      int r = tid >> 2, cs = (tid & 3) * 32;
      unsigned short* dst = xb + r * LDP + cs;
      if (r0 + r < N) {
        const float4* xp = (const float4*)(x + (((size_t)(r0 + r) * 8 + hh) << 7) + cs);
#pragma unroll
        for (int j = 0; j < 8; j++) {
          float4 f = xp[j];
          ushort4 sv = {f2bf(f.x), f2bf(f.y), f2bf(f.z), f2bf(f.w)};
          ((ushort4*)dst)[j] = sv;
        }
      } else {
        ushort4 zz = {0, 0, 0, 0};
#pragma unroll
        for (int j = 0; j < 8; j++) ((ushort4*)dst)[j] = zz;
      }
    }
    __syncthreads();

    // GEMM1
    f32x4 acc[8] = {};
    {
      const unsigned short* arow = xb + (wv * 16 + m) * LDP + q * 8;
      const unsigned short* bbase = w1s + m * LDP + q * 8;
#pragma unroll
      for (int kk = 0; kk < 4; kk++) {
        bf16x8 af = *(const bf16x8*)(arow + kk * 32);
#pragma unroll
        for (int nt = 0; nt < 8; nt++) {
          bf16x8 bfr = *(const bf16x8*)(bbase + nt * 16 * LDP + kk * 32);
          acc[nt] = __builtin_amdgcn_mfma_f32_16x16x32_bf16(af, bfr, acc[nt], 0, 0, 0);
        }
      }
    }
    __syncthreads();  // all xb reads done; safe to overwrite with hb

    // affine (BN folded) + ReLU -> bf16 into LDS (C-layout -> A-layout round-trip)
    {
      const int rowl = wv * 16 + q * 4;
#pragma unroll
      for (int nt = 0; nt < 8; nt++) {
        int c = nt * 16 + m;
        float a = acs[c], b = bcs[c];
#pragma unroll
        for (int r = 0; r < 4; r++) {
          float v = fmaxf(fmaf(acc[nt][r], a, b), 0.f);
          xb[(rowl + r) * LDP + c] = f2bf(v);
        }
      }
    }
    __syncthreads();

    // GEMM2: [16 x 128] @ [128 x 64]
    f32x4 acc2[4] = {};
    {
      const unsigned short* arow = xb + (wv * 16 + m) * LDP + q * 8;
      const unsigned short* bbase = w2s + m * LDP + q * 8;
#pragma unroll
      for (int kk = 0; kk < 4; kk++) {
        bf16x8 af = *(const bf16x8*)(arow + kk * 32);
#pragma unroll
        for (int nt = 0; nt < 4; nt++) {
          bf16x8 bfr = *(const bf16x8*)(bbase + nt * 16 * LDP + kk * 32);
          acc2[nt] = __builtin_amdgcn_mfma_f32_16x16x32_bf16(af, bfr, acc2[nt], 0, 0, 0);
        }
      }
    }

    // epilogue: + b2, store y[row][hh][col]
    {
      const int rowg = r0 + wv * 16 + q * 4;
#pragma unroll
      for (int nt = 0; nt < 4; nt++) {
        int col = nt * 16 + m;
        float bias = b2s[col];
#pragma unroll
        for (int r = 0; r < 4; r++) {
          int row = rowg + r;
          if (row < N) y[((size_t)row * 8 + hh) * 64 + col] = acc2[nt][r] + bias;
        }
      }
    }
  }
}

extern "C" void kernel_launch(void* const* d_in, const int* in_sizes, int n_in,
                              void* d_out, int out_size, void* d_ws, size_t ws_size,
                              hipStream_t stream) {
  const float* x = (const float*)d_in[0];
  const float* w1 = (const float*)d_in[1];
  const float* b1 = (const float*)d_in[2];
  const float* bnw = (const float*)d_in[3];
  const float* bnb = (const float*)d_in[4];
  const float* w2 = (const float*)d_in[5];
  const float* b2 = (const float*)d_in[6];
  float* y = (float*)d_out;

  const int N = in_sizes[0] / (H_HEADS * F_IN);
  const int nblk = (N + 255) / 256;  // each block covers 4 chunks of 64 rows

  unsigned short* w1bf = (unsigned short*)d_ws;
  unsigned short* w2bf = w1bf + H_HEADS * 128 * 128;
  float* partial = (float*)(w2bf + H_HEADS * 64 * 128);
  float* acoef = partial + (size_t)H_HEADS * nblk * 256;
  float* bcoef = acoef + 1024;

  k_prep<<<512, 256, 0, stream>>>(w1, w2, w1bf, w2bf);
  k_stats<<<dim3(nblk, H_HEADS), 256, 0, stream>>>(x, w1bf, b1, partial, N, nblk);
  k_fin<<<8, 256, 0, stream>>>(partial, b1, bnw, bnb, acoef, bcoef, N, nblk);
  k_main<<<dim3(nblk, H_HEADS), 256, 0, stream>>>(x, w1bf, w2bf, acoef, bcoef, b2, y, N, nblk);
}